// Round 1
// baseline (106.945 us; speedup 1.0000x reference)
//
#include <hip/hip_runtime.h>

// HEAQNetwork: batched 4-qubit, 3-layer circuit. State = 16 complex amps per
// element, held entirely in registers (re[16], im[16]). Qubit q <-> bit (3-q)
// of the flat index (qubit 0 = outermost axis of the (2,2,2,2) state).

constexpr int NQ = 4;
constexpr int NL = 3;

// 12 batch-uniform RY(weights) cos/sin pairs -> d_ws
__global__ void heaq_cs_kernel(const float* __restrict__ weights,
                               float* __restrict__ cs) {
    int t = threadIdx.x;
    if (t < NL * NQ) {
        float h = 0.5f * weights[t];
        cs[2 * t]     = cosf(h);
        cs[2 * t + 1] = sinf(h);
    }
}

__global__ __launch_bounds__(256) void heaq_kernel(
    const float4* __restrict__ x4,
    const float*  __restrict__ w_input,
    const float*  __restrict__ cs,
    const float*  __restrict__ w_output,
    float2*       __restrict__ out2,
    int B)
{
    int b = blockIdx.x * 256 + threadIdx.x;
    if (b >= B) return;

    // angles[q] = atan(x[q] * w_input[q]); need cos/sin of half-angle.
    // r = cos(theta) = rsqrt(1+u^2); ch = sqrt((1+r)/2); sh = u*r/(2*ch).
    float4 xv = x4[b];
    float xs[4] = {xv.x, xv.y, xv.z, xv.w};
    float ch[4], sh[4];
#pragma unroll
    for (int q = 0; q < 4; ++q) {
        float u = xs[q] * w_input[q];
        float r = rsqrtf(1.0f + u * u);
        float c = sqrtf(0.5f * (1.0f + r));
        ch[q] = c;
        sh[q] = 0.5f * u * r / c;
    }

    float re[16], im[16];
#pragma unroll
    for (int i = 0; i < 16; ++i) { re[i] = 0.0f; im[i] = 0.0f; }
    re[0] = 1.0f;

#pragma unroll
    for (int layer = 0; layer < NL; ++layer) {
        // RX(angles[q]) on qubit q:  [[c, -i s], [-i s, c]]
#pragma unroll
        for (int q = 0; q < 4; ++q) {
            const int st = 8 >> q;
            const float c = ch[q], s = sh[q];
#pragma unroll
            for (int i = 0; i < 16; ++i) {
                if (i & st) continue;
                const int j = i | st;
                float a0r = re[i], a0i = im[i], a1r = re[j], a1i = im[j];
                re[i] = c * a0r + s * a1i;
                im[i] = c * a0i - s * a1r;
                re[j] = c * a1r + s * a0i;
                im[j] = c * a1i - s * a0r;
            }
        }
        // RY(weights[layer][q]) on qubit q:  [[c, -s], [s, c]] (real)
#pragma unroll
        for (int q = 0; q < 4; ++q) {
            const float c = cs[2 * (layer * 4 + q)];
            const float s = cs[2 * (layer * 4 + q) + 1];
            const int st = 8 >> q;
#pragma unroll
            for (int i = 0; i < 16; ++i) {
                if (i & st) continue;
                const int j = i | st;
                float a0r = re[i], a0i = im[i], a1r = re[j], a1i = im[j];
                re[i] = c * a0r - s * a1r;
                im[i] = c * a0i - s * a1i;
                re[j] = s * a0r + c * a1r;
                im[j] = s * a0i + c * a1i;
            }
        }
        // CNOT(q, q+1) chain: swap amps where ctrl bit set, flipping tgt bit.
        // Free: compile-time register renames.
#pragma unroll
        for (int cq = 0; cq < 3; ++cq) {
            const int cm = 8 >> cq;
            const int tm = 8 >> (cq + 1);
#pragma unroll
            for (int i = 0; i < 16; ++i) {
                if ((i & cm) && !(i & tm)) {
                    const int j = i | tm;
                    float t;
                    t = re[i]; re[i] = re[j]; re[j] = t;
                    t = im[i]; im[i] = im[j]; im[j] = t;
                }
            }
        }
    }

    // <Z_w>: qubit 0 -> bit 3 (i&8), qubit 1 -> bit 2 (i&4)
    float z0 = 0.0f, z1 = 0.0f;
#pragma unroll
    for (int i = 0; i < 16; ++i) {
        float p = re[i] * re[i] + im[i] * im[i];
        z0 += (i & 8) ? -p : p;
        z1 += (i & 4) ? -p : p;
    }
    float w0 = w_output[0], w1 = w_output[1];
    out2[b] = make_float2(0.5f * w0 * (1.0f + z0), 0.5f * w1 * (1.0f + z1));
}

extern "C" void kernel_launch(void* const* d_in, const int* in_sizes, int n_in,
                              void* d_out, int out_size, void* d_ws, size_t ws_size,
                              hipStream_t stream) {
    const float* x        = (const float*)d_in[0];
    const float* w_input  = (const float*)d_in[1];
    const float* weights  = (const float*)d_in[2];
    const float* w_output = (const float*)d_in[3];
    float* out = (float*)d_out;
    float* cs  = (float*)d_ws;   // 24 floats

    const int B = in_sizes[0] / 4;

    heaq_cs_kernel<<<1, 64, 0, stream>>>(weights, cs);
    heaq_kernel<<<(B + 255) / 256, 256, 0, stream>>>(
        (const float4*)x, w_input, cs, w_output, (float2*)out, B);
}

// Round 2
// 86.571 us; speedup vs baseline: 1.2353x; 1.2353x over previous
//
#include <hip/hip_runtime.h>

// HEAQNetwork: batched 4-qubit, 3-layer circuit, 16 complex amps per element
// held entirely in registers. Qubit q <-> bit (3-q) of the flat index.
//
// Exact algebraic reductions vs the naive circuit:
//  * Layer 1 acts on |0000>: build product state from per-qubit RY*RX|0>
//    2-vectors (tensor build ~140 ops vs 512).
//  * Measured ops are Z0 and (Z1 pulled through layer-3 CNOT(0,1)) Z0Z1,
//    support {0,1}: drop ALL layer-3 CNOTs and layer-3 gates on qubits 2,3.
//    Signs: out0 ~ (-1)^b3, out1 ~ (-1)^(b3^b2).
//  * Pulled back through layer-2's CNOT chain the operators have support
//    {0,1,2}: drop layer-2 RX3/RY3 and CNOT(2,3).

__device__ __forceinline__ void apply_rx(float (&re)[16], float (&im)[16],
                                         float c, float s, const int st) {
#pragma unroll
    for (int i = 0; i < 16; ++i) {
        if (i & st) continue;
        const int j = i | st;
        float a0r = re[i], a0i = im[i], a1r = re[j], a1i = im[j];
        re[i] = c * a0r + s * a1i;
        im[i] = c * a0i - s * a1r;
        re[j] = c * a1r + s * a0i;
        im[j] = c * a1i - s * a0r;
    }
}

__device__ __forceinline__ void apply_ry(float (&re)[16], float (&im)[16],
                                         float c, float s, const int st) {
#pragma unroll
    for (int i = 0; i < 16; ++i) {
        if (i & st) continue;
        const int j = i | st;
        float a0r = re[i], a0i = im[i], a1r = re[j], a1i = im[j];
        re[i] = c * a0r - s * a1r;
        im[i] = c * a0i - s * a1i;
        re[j] = s * a0r + c * a1r;
        im[j] = s * a0i + c * a1i;
    }
}

__device__ __forceinline__ void apply_cnot(float (&re)[16], float (&im)[16],
                                           const int cm, const int tm) {
#pragma unroll
    for (int i = 0; i < 16; ++i) {
        if ((i & cm) && !(i & tm)) {
            const int j = i | tm;
            float t;
            t = re[i]; re[i] = re[j]; re[j] = t;
            t = im[i]; im[i] = im[j]; im[j] = t;
        }
    }
}

__global__ __launch_bounds__(256) void heaq_kernel(
    const float4* __restrict__ x4,
    const float*  __restrict__ w_input,
    const float*  __restrict__ weights,
    const float*  __restrict__ w_output,
    float2*       __restrict__ out2,
    int B)
{
    int b = blockIdx.x * 256 + threadIdx.x;
    if (b >= B) return;

    // ---- RX half-angle cos/sin per qubit (angles reused every layer) ----
    // theta = atan(u):  r = cos(theta) = rsqrt(1+u^2)
    //   ch = sqrt((1+r)/2);  sh = u*r/(2*ch)   (rcp instead of div sequence)
    float4 xv = x4[b];
    float xs[4] = {xv.x, xv.y, xv.z, xv.w};
    float cx[4], sxv[4];
#pragma unroll
    for (int q = 0; q < 4; ++q) {
        float u = xs[q] * w_input[q];
        float r = __builtin_amdgcn_rsqf(__builtin_fmaf(u, u, 1.0f));
        float c = __builtin_amdgcn_sqrtf(__builtin_fmaf(0.5f, r, 0.5f));
        cx[q] = c;
        sxv[q] = 0.5f * u * r * __builtin_amdgcn_rcpf(c);
    }

    // ---- RY half-angle cos/sin (batch-uniform weights), v_sin/v_cos in
    // revolutions: rev = (w/2) / (2*pi) ----
    const float K = 0.07957747154594767f;
    float cy[12], sy[12];
#pragma unroll
    for (int t = 0; t < 12; ++t) {
        float rev = __builtin_amdgcn_fractf(weights[t] * K);
        cy[t] = __builtin_amdgcn_cosf(rev);
        sy[t] = __builtin_amdgcn_sinf(rev);
    }

    // ---- Layer 1 as product state: v_q = RY(w0q) RX(aq) |0> ----
    // v = (cy*cx + i sy*sx,  sy*cx - i cy*sx)
    float vr[4][2], vi[4][2];
#pragma unroll
    for (int q = 0; q < 4; ++q) {
        vr[q][0] = cy[q] * cx[q];
        vi[q][0] = sy[q] * sxv[q];
        vr[q][1] = sy[q] * cx[q];
        vi[q][1] = -cy[q] * sxv[q];
    }
    // amp[b3b2b1b0] = v0[b3] v1[b2] v2[b1] v3[b0]
    float p2r[4], p2i[4];
#pragma unroll
    for (int i = 0; i < 4; ++i) {
        const int a = i >> 1, c = i & 1;
        p2r[i] = vr[0][a] * vr[1][c] - vi[0][a] * vi[1][c];
        p2i[i] = vr[0][a] * vi[1][c] + vi[0][a] * vr[1][c];
    }
    float p3r[8], p3i[8];
#pragma unroll
    for (int i = 0; i < 8; ++i) {
        const int h = i >> 1, c = i & 1;
        p3r[i] = p2r[h] * vr[2][c] - p2i[h] * vi[2][c];
        p3i[i] = p2r[h] * vi[2][c] + p2i[h] * vr[2][c];
    }
    float re[16], im[16];
#pragma unroll
    for (int i = 0; i < 16; ++i) {
        const int h = i >> 1, c = i & 1;
        re[i] = p3r[h] * vr[3][c] - p3i[h] * vi[3][c];
        im[i] = p3r[h] * vi[3][c] + p3i[h] * vr[3][c];
    }
    // Layer-1 CNOT chain (register renames)
    apply_cnot(re, im, 8, 4);
    apply_cnot(re, im, 4, 2);
    apply_cnot(re, im, 2, 1);

    // ---- Layer 2: qubits 0,1,2 only (q3 gates pruned) ----
    apply_rx(re, im, cx[0], sxv[0], 8);
    apply_rx(re, im, cx[1], sxv[1], 4);
    apply_rx(re, im, cx[2], sxv[2], 2);
    apply_ry(re, im, cy[4], sy[4], 8);
    apply_ry(re, im, cy[5], sy[5], 4);
    apply_ry(re, im, cy[6], sy[6], 2);
    apply_cnot(re, im, 8, 4);
    apply_cnot(re, im, 4, 2);
    // CNOT(2,3) pruned (commutes with measured operators)

    // ---- Layer 3: qubits 0,1 only; CNOTs folded into measurement signs ----
    apply_rx(re, im, cx[0], sxv[0], 8);
    apply_rx(re, im, cx[1], sxv[1], 4);
    apply_ry(re, im, cy[8], sy[8], 8);
    apply_ry(re, im, cy[9], sy[9], 4);

    // out0 = <Z0> = sum (-1)^b3 p;  out1 = <Z0 Z1> = sum (-1)^(b3^b2) p
    float z0 = 0.0f, z1 = 0.0f;
#pragma unroll
    for (int i = 0; i < 16; ++i) {
        float p = re[i] * re[i] + im[i] * im[i];
        z0 += (i & 8) ? -p : p;
        z1 += (((i >> 3) ^ (i >> 2)) & 1) ? -p : p;
    }
    float w0 = w_output[0], w1 = w_output[1];
    out2[b] = make_float2(0.5f * w0 * (1.0f + z0), 0.5f * w1 * (1.0f + z1));
}

extern "C" void kernel_launch(void* const* d_in, const int* in_sizes, int n_in,
                              void* d_out, int out_size, void* d_ws, size_t ws_size,
                              hipStream_t stream) {
    const float* x        = (const float*)d_in[0];
    const float* w_input  = (const float*)d_in[1];
    const float* weights  = (const float*)d_in[2];
    const float* w_output = (const float*)d_in[3];
    float* out = (float*)d_out;

    const int B = in_sizes[0] / 4;

    heaq_kernel<<<(B + 255) / 256, 256, 0, stream>>>(
        (const float4*)x, w_input, weights, w_output, (float2*)out, B);
}

// Round 3
// 84.715 us; speedup vs baseline: 1.2624x; 1.0219x over previous
//
#include <hip/hip_runtime.h>
#include <hip/hip_fp16.h>

// HEAQNetwork: batched 4-qubit, 3-layer circuit. After pruning (see R2),
// no gate touches qubit 3 beyond layer 1, so the 16 amps pack as 8 __half2
// (SoA over bit0 of the flat index) and every gate is elementwise packed
// f16 math (v_pk_fma_f16 = 2 FMA/lane/instr). Layer-1 product-state build
// and measurement accumulate stay fp32; layer-1 CNOT chain is folded into
// the build permutation J (compile time).
//
// index i = (b3 b2 b1 b0), qubit q <-> bit (3-q). Packed reg k = i>>1.
// qubit0 -> k mask 4, qubit1 -> 2, qubit2 -> 1.

__device__ __forceinline__ float rdlane(float x, int l) {
    return __int_as_float(__builtin_amdgcn_readlane(__float_as_int(x), l));
}
__device__ __forceinline__ __half2 dup2(float f) {
    return __half2half2(__float2half(f));
}

// RX: [[c, -i s],[-i s, c]] on packed pairs (k, k|m)
__device__ __forceinline__ void rx2(__half2 (&re2)[8], __half2 (&im2)[8],
                                    __half2 c, __half2 s, const int m) {
    __half2 ns = __hneg2(s);
#pragma unroll
    for (int k = 0; k < 8; ++k) {
        if (k & m) continue;
        const int k1 = k | m;
        __half2 r0 = re2[k], i0 = im2[k], r1 = re2[k1], i1 = im2[k1];
        re2[k]  = __hfma2(c, r0, __hmul2(s,  i1));
        im2[k]  = __hfma2(c, i0, __hmul2(ns, r1));
        re2[k1] = __hfma2(c, r1, __hmul2(s,  i0));
        im2[k1] = __hfma2(c, i1, __hmul2(ns, r0));
    }
}

// RY: [[c, -s],[s, c]] (real) on packed pairs (k, k|m)
__device__ __forceinline__ void ry2(__half2 (&re2)[8], __half2 (&im2)[8],
                                    __half2 c, __half2 s, const int m) {
    __half2 ns = __hneg2(s);
#pragma unroll
    for (int k = 0; k < 8; ++k) {
        if (k & m) continue;
        const int k1 = k | m;
        __half2 r0 = re2[k], i0 = im2[k], r1 = re2[k1], i1 = im2[k1];
        re2[k]  = __hfma2(c, r0, __hmul2(ns, r1));
        im2[k]  = __hfma2(c, i0, __hmul2(ns, i1));
        re2[k1] = __hfma2(s, r0, __hmul2(c, r1));
        im2[k1] = __hfma2(s, i0, __hmul2(c, i1));
    }
}

__device__ __forceinline__ void swap2(__half2 (&a)[8], int x, int y) {
    __half2 t = a[x]; a[x] = a[y]; a[y] = t;
}

__global__ __launch_bounds__(256) void heaq_kernel(
    const float4* __restrict__ x4,
    const float*  __restrict__ w_input,
    const float*  __restrict__ weights,
    const float*  __restrict__ w_output,
    float2*       __restrict__ out2,
    int B)
{
    const int lane = threadIdx.x & 63;

    // ---- batch-uniform RY half-angle sincos: lanes 0..11 compute, then
    // readlane -> SGPR broadcasts. Done BEFORE the bounds check so every
    // lane of a partially-masked wave has valid values. ----
    const float K = 0.07957747154594767f;  // 1/(4*pi): rev = (w/2)/(2*pi)
    float wv  = weights[lane < 12 ? lane : 0];
    float rev = __builtin_amdgcn_fractf(wv * K);
    float sn  = __builtin_amdgcn_sinf(rev);
    float cn  = __builtin_amdgcn_cosf(rev);

    // layer 1 (fp32): t = 0..3
    float cy0 = rdlane(cn, 0), sy0 = rdlane(sn, 0);
    float cy1 = rdlane(cn, 1), sy1 = rdlane(sn, 1);
    float cy2 = rdlane(cn, 2), sy2 = rdlane(sn, 2);
    float cy3 = rdlane(cn, 3), sy3 = rdlane(sn, 3);
    // layer 2 (f16): t = 4,5,6 ; layer 3: t = 8,9
    __half2 cy4h = dup2(rdlane(cn, 4)), sy4h = dup2(rdlane(sn, 4));
    __half2 cy5h = dup2(rdlane(cn, 5)), sy5h = dup2(rdlane(sn, 5));
    __half2 cy6h = dup2(rdlane(cn, 6)), sy6h = dup2(rdlane(sn, 6));
    __half2 cy8h = dup2(rdlane(cn, 8)), sy8h = dup2(rdlane(sn, 8));
    __half2 cy9h = dup2(rdlane(cn, 9)), sy9h = dup2(rdlane(sn, 9));

    const int b = blockIdx.x * 256 + threadIdx.x;
    if (b >= B) return;

    // ---- RX half-angle cos/sin per qubit (fp32) ----
    // theta = atan(u): r = cos = rsqrt(1+u^2); ch = sqrt((1+r)/2);
    // sh = u*r/(2*ch)
    float4 xv = x4[b];
    float xs[4] = {xv.x, xv.y, xv.z, xv.w};
    float cx[4], sx[4];
#pragma unroll
    for (int q = 0; q < 4; ++q) {
        float u = xs[q] * w_input[q];
        float r = __builtin_amdgcn_rsqf(__builtin_fmaf(u, u, 1.0f));
        float c = __builtin_amdgcn_sqrtf(__builtin_fmaf(0.5f, r, 0.5f));
        cx[q] = c;
        sx[q] = 0.5f * u * r * __builtin_amdgcn_rcpf(c);
    }
    __half2 cxh[3], sxh[3];
#pragma unroll
    for (int q = 0; q < 3; ++q) { cxh[q] = dup2(cx[q]); sxh[q] = dup2(sx[q]); }

    // ---- Layer 1 (fp32): product state v_q = RY RX |0> ----
    // v = (cy*cx + i sy*sx,  sy*cx - i cy*sx)
    float cys[4] = {cy0, cy1, cy2, cy3};
    float sys[4] = {sy0, sy1, sy2, sy3};
    float vr[4][2], vi[4][2];
#pragma unroll
    for (int q = 0; q < 4; ++q) {
        vr[q][0] = cys[q] * cx[q];
        vi[q][0] = sys[q] * sx[q];
        vr[q][1] = sys[q] * cx[q];
        vi[q][1] = -cys[q] * sx[q];
    }
    float p2r[4], p2i[4];
#pragma unroll
    for (int i = 0; i < 4; ++i) {
        const int a = i >> 1, c = i & 1;
        p2r[i] = vr[0][a] * vr[1][c] - vi[0][a] * vi[1][c];
        p2i[i] = vr[0][a] * vi[1][c] + vi[0][a] * vr[1][c];
    }
    float p3r[8], p3i[8];
#pragma unroll
    for (int i = 0; i < 8; ++i) {
        const int h = i >> 1, c = i & 1;
        p3r[i] = p2r[h] * vr[2][c] - p2i[h] * vi[2][c];
        p3i[i] = p2r[h] * vi[2][c] + p2i[h] * vr[2][c];
    }

    // ---- Final tensor step with layer-1 CNOT chain folded in.
    // j(i): j3=i3, j2=i2^i3, j1=i1^i2^i3, j0=i0^..^i3 -> pre-pair h goes to
    // packed reg T[h], halves swapped if SW[h]. Pack fp32 -> __half2 here.
    constexpr int T[8]  = {0, 1, 3, 2, 7, 6, 4, 5};
    constexpr int SW[8] = {0, 1, 1, 0, 1, 0, 0, 1};
    __half2 re2[8], im2[8];
#pragma unroll
    for (int h = 0; h < 8; ++h) {
        float a0r = p3r[h] * vr[3][0] - p3i[h] * vi[3][0];
        float a0i = p3r[h] * vi[3][0] + p3i[h] * vr[3][0];
        float a1r = p3r[h] * vr[3][1] - p3i[h] * vi[3][1];
        float a1i = p3r[h] * vi[3][1] + p3i[h] * vr[3][1];
        const int t = T[h];
        if (SW[h]) {
            re2[t] = __floats2half2_rn(a1r, a0r);
            im2[t] = __floats2half2_rn(a1i, a0i);
        } else {
            re2[t] = __floats2half2_rn(a0r, a1r);
            im2[t] = __floats2half2_rn(a0i, a1i);
        }
    }

    // ---- Layer 2 (packed f16): qubits 0,1,2 ----
    rx2(re2, im2, cxh[0], sxh[0], 4);
    rx2(re2, im2, cxh[1], sxh[1], 2);
    rx2(re2, im2, cxh[2], sxh[2], 1);
    ry2(re2, im2, cy4h, sy4h, 4);
    ry2(re2, im2, cy5h, sy5h, 2);
    ry2(re2, im2, cy6h, sy6h, 1);
    // CNOT(0,1): swap k 4<->6, 5<->7 ; CNOT(1,2): swap k 2<->3, 6<->7
    swap2(re2, 4, 6); swap2(im2, 4, 6);
    swap2(re2, 5, 7); swap2(im2, 5, 7);
    swap2(re2, 2, 3); swap2(im2, 2, 3);
    swap2(re2, 6, 7); swap2(im2, 6, 7);

    // ---- Layer 3 (packed f16): qubits 0,1 only ----
    rx2(re2, im2, cxh[0], sxh[0], 4);
    rx2(re2, im2, cxh[1], sxh[1], 2);
    ry2(re2, im2, cy8h, sy8h, 4);
    ry2(re2, im2, cy9h, sy9h, 2);

    // ---- Measurement: z0 sign (-1)^(k bit2), z1 sign (-1)^(k bit2 ^ bit1)
    float z0 = 0.0f, z1 = 0.0f;
#pragma unroll
    for (int k = 0; k < 8; ++k) {
        __half2 p = __hfma2(re2[k], re2[k], __hmul2(im2[k], im2[k]));
        float2 pf = __half22float2(p);
        float ps = pf.x + pf.y;
        if (k & 4) z0 -= ps; else z0 += ps;
        if (((k >> 2) ^ (k >> 1)) & 1) z1 -= ps; else z1 += ps;
    }
    float w0 = w_output[0], w1 = w_output[1];
    out2[b] = make_float2(0.5f * w0 * (1.0f + z0), 0.5f * w1 * (1.0f + z1));
}

extern "C" void kernel_launch(void* const* d_in, const int* in_sizes, int n_in,
                              void* d_out, int out_size, void* d_ws, size_t ws_size,
                              hipStream_t stream) {
    const float* x        = (const float*)d_in[0];
    const float* w_input  = (const float*)d_in[1];
    const float* weights  = (const float*)d_in[2];
    const float* w_output = (const float*)d_in[3];
    float* out = (float*)d_out;

    const int B = in_sizes[0] / 4;

    heaq_kernel<<<(B + 255) / 256, 256, 0, stream>>>(
        (const float4*)x, w_input, weights, w_output, (float2*)out, B);
}